// Round 12
// baseline (154.026 us; speedup 1.0000x reference)
//
#include <hip/hip_runtime.h>

#define NN 1000
#define HEADS_ 4
#define DM 128
#define EE 64000
#define NTOT 4000
#define ETOT 68000
#define CAP 48     // bucket: deg ~ Poisson(16)+1, P(>=48) ~ 1e-11
#define EB 34      // edge-builder blocks appended to k1

// ---------------------------------------------------------------------------
// Tiled GEMM tile: C[m0..+128][n0..+64] = A @ Wt^T (+b1), K in {64,128}.
// LDS m-major with k-group swizzle g = q ^ ((r>>2)&15) (all accesses <=2-way).
// SCORE: GAT score epilogue (h rows<1000 are the only nonzero h_flat rows).
// ---------------------------------------------------------------------------
template <int K, int SCORE>
__device__ void gemm_tile(int mi, int ni,
                          const float* __restrict__ A, const float* __restrict__ Wt,
                          const float* __restrict__ b1,
                          float* __restrict__ C, int N,
                          const float* __restrict__ att,
                          float* __restrict__ ssrc, float* __restrict__ sdst) {
  __shared__ float As[128 * 64];
  __shared__ float Bs[64 * 64];
  int tid = threadIdx.x;
  int m0 = mi * 128, n0 = ni * 64;
  int tx = tid & 15, ty = tid >> 4;
  const float4* A4 = (const float4*)A;
  const float4* W4 = (const float4*)Wt;
  float acc[8][4] = {};

  for (int c = 0; c < K / 64; ++c) {
    __syncthreads();
    {
      int q = tid & 15;   // k-group slot within chunk
      int r0 = tid >> 4;  // 16 rows per pass
#pragma unroll
      for (int p = 0; p < 8; ++p) {  // A: 128 rows
        int r = r0 + p * 16;
        float4 v = A4[(size_t)(m0 + r) * (K / 4) + c * 16 + q];
        *(float4*)&As[r * 64 + ((q ^ ((r >> 2) & 15)) << 2)] = v;
      }
#pragma unroll
      for (int p = 0; p < 4; ++p) {  // B: 64 rows
        int r = r0 + p * 16;
        float4 v = W4[(size_t)(n0 + r) * (K / 4) + c * 16 + q];
        *(float4*)&Bs[r * 64 + ((q ^ ((r >> 2) & 15)) << 2)] = v;
      }
    }
    __syncthreads();
#pragma unroll 4
    for (int q = 0; q < 16; ++q) {
      float4 a[8], b[4];
#pragma unroll
      for (int i = 0; i < 8; ++i) {
        int r = ty * 8 + i;
        a[i] = *(const float4*)&As[r * 64 + ((q ^ ((r >> 2) & 15)) << 2)];
      }
#pragma unroll
      for (int j = 0; j < 4; ++j) {
        int rn = tx * 4 + j;
        b[j] = *(const float4*)&Bs[rn * 64 + ((q ^ ((rn >> 2) & 15)) << 2)];
      }
#pragma unroll
      for (int i = 0; i < 8; ++i)
#pragma unroll
        for (int j = 0; j < 4; ++j)
          acc[i][j] += a[i].x * b[j].x + a[i].y * b[j].y
                     + a[i].z * b[j].z + a[i].w * b[j].w;
    }
  }

  float bd[4] = {0.f, 0.f, 0.f, 0.f};
  int nc = n0 + tx * 4;
  if (b1) { bd[0] = b1[nc]; bd[1] = b1[nc+1]; bd[2] = b1[nc+2]; bd[3] = b1[nc+3]; }
#pragma unroll
  for (int i = 0; i < 8; ++i) {
    int m = m0 + ty * 8 + i;
    float4 o = make_float4(acc[i][0] + bd[0], acc[i][1] + bd[1],
                           acc[i][2] + bd[2], acc[i][3] + bd[3]);
    *(float4*)&C[(size_t)m * N + nc] = o;
  }

  if (SCORE && m0 < NN) {  // uniform per block
    int hsel = tx >> 3;
    int h = ni * 2 + hsel;
    int kb = (tx & 7) * 4;
    float a0[4], a1[4];
#pragma unroll
    for (int j = 0; j < 4; ++j) {
      a0[j] = att[h * 64 + kb + j];
      a1[j] = att[h * 64 + 32 + kb + j];
    }
#pragma unroll
    for (int i = 0; i < 8; ++i) {
      int m = m0 + ty * 8 + i;
      float p0 = 0.f, p1 = 0.f;
#pragma unroll
      for (int j = 0; j < 4; ++j) {
        float g = acc[i][j];
        float lr = g > 0.f ? g : 0.2f * g;
        p0 += a0[j] * lr;
        p1 += a1[j] * lr;
      }
      p0 += __shfl_xor(p0, 1, 16); p1 += __shfl_xor(p1, 1, 16);
      p0 += __shfl_xor(p0, 2, 16); p1 += __shfl_xor(p1, 2, 16);
      p0 += __shfl_xor(p0, 4, 16); p1 += __shfl_xor(p1, 4, 16);
      if ((tx & 7) == 0 && m < NN) {
        ssrc[m * HEADS_ + h] = p0;
        sdst[m * HEADS_ + h] = p1;
      }
    }
  }
}

// -------- K1: blocks 0..249 = h-GEMM (125x2 tiles) + score epilogue
//              blocks 250..249+EB = bucket build
__global__ __launch_bounds__(256) void k1_kernel(const float* __restrict__ x,
                                                 const float* __restrict__ W,
                                                 const float* __restrict__ att,
                                                 float* __restrict__ hbuf,
                                                 float* __restrict__ ssrc,
                                                 float* __restrict__ sdst,
                                                 const int* __restrict__ ei,
                                                 int* __restrict__ cnt,
                                                 int* __restrict__ elist) {
  int bid = blockIdx.x;
  if (bid < 250) {
    gemm_tile<64, 1>(bid >> 1, bid & 1, x, W, nullptr, hbuf, 128, att, ssrc, sdst);
  } else {
    for (int e = (bid - 250) * 256 + threadIdx.x; e < ETOT; e += EB * 256) {
      int s, d;
      if (e < EE) { s = ei[e]; d = ei[EE + e]; }
      else { s = d = e - EE; }  // self loops
      int pos = atomicAdd(&cnt[d], 1);
      if (pos < CAP) elist[d * CAP + pos] = s;
    }
  }
}

// -------- K2: gather with in-block softmax (local denom), 2 dst/block
__global__ __launch_bounds__(256) void gather_kernel(const int* __restrict__ cnt,
                                                     const int* __restrict__ elist,
                                                     const float* __restrict__ ssrc,
                                                     const float* __restrict__ sdst,
                                                     const float* __restrict__ hbuf,
                                                     float* __restrict__ hgat) {
  __shared__ int   srcs[2][CAP];
  __shared__ float exs[2][CAP][HEADS_];
  int li = threadIdx.x >> 7;
  int t = threadIdx.x & 127;
  int d = blockIdx.x * 2 + li;  // global dst node id
  int b = d / NN;
  int v = t >> 5, q = t & 31, h = q >> 3;
  int m = cnt[d]; if (m > CAP) m = CAP;
  for (int base = 0; base < m; base += 32) {  // 4 threads per edge
    int i = base + (t >> 2);
    if (i < m) {
      int s = elist[d * CAP + i];
      if ((t & 3) == 0) srcs[li][i] = s;
      float sc = ssrc[s * HEADS_ + (t & 3)] + sdst[d * HEADS_ + (t & 3)];
      exs[li][i][t & 3] = __expf(sc);  // shift-invariant, scores O(1)
    }
  }
  __syncthreads();
  // denom over ALL edges; numerator over same-block srcs (h_full block-diag)
  float den = 1e-16f;
  float4 acc = make_float4(0.f, 0.f, 0.f, 0.f);
  const float* hbase = hbuf + ((size_t)(b * 4 + v) * NN) * DM + q * 4;
  for (int i = 0; i < m; ++i) {
    float ex = exs[li][i][h];
    den += ex;
    unsigned sl = (unsigned)(srcs[li][i] - b * NN);
    if (sl < NN) {
      float4 hv = *(const float4*)(hbase + (size_t)sl * DM);
      acc.x += ex * hv.x; acc.y += ex * hv.y;
      acc.z += ex * hv.z; acc.w += ex * hv.w;
    }
  }
  float r = 1.f / den;
  acc.x *= r; acc.y *= r; acc.z *= r; acc.w *= r;
  *(float4*)&hgat[((size_t)(d * 4 + v)) * DM + q * 4] = acc;  // node-major
}

// -------- K3: qkv GEMM wrapper (node-major, M=16000, K=128, N=384)
__global__ __launch_bounds__(256) void qkv_kernel(const float* __restrict__ hgat,
                                                  const float* __restrict__ inw,
                                                  const float* __restrict__ inb,
                                                  float* __restrict__ qkv) {
  gemm_tile<128, 0>(blockIdx.x, blockIdx.y, hgat, inw, inb, qkv, 384,
                    nullptr, nullptr, nullptr);
}

// -------- K4: attention over V + fused out_proj, 2 nodes/block.
// outw staged in LDS in two 32KB k-halves with float4 swizzle (k4+j)&15:
// staging writes (j fixed per 16-lane group, k4=0..15) and compute reads
// (j consecutive, k4 fixed) both cover all 16 float4 bank-groups -> no
// conflicts. ao reads are same-address broadcast.
__global__ __launch_bounds__(256) void attn_out_kernel(const float* __restrict__ qkv,
                                                       const float* __restrict__ outw,
                                                       const float* __restrict__ outb,
                                                       const float* __restrict__ bias,
                                                       float* __restrict__ out) {
  __shared__ float qs[2][4][DM], ks[2][4][DM], vs[2][4][DM];
  __shared__ float aw[2][4][HEADS_][4];
  __shared__ float ao_s[2][4][DM];            // attention output (pre-proj)
  __shared__ float owt[64 * 128];             // one 32KB k-half of outw, swizzled
  int tid = threadIdx.x;
  int li = tid >> 7;
  int t = tid & 127;
  int node = blockIdx.x * 2 + li;  // 0..3999
  int b = node / NN, n = node - b * NN;
#pragma unroll
  for (int v = 0; v < 4; ++v) {
    size_t base = (size_t)(node * 4 + v) * 384;  // node-major, contiguous
    qs[li][v][t] = qkv[base + t];
    ks[li][v][t] = qkv[base + 128 + t];
    vs[li][v][t] = qkv[base + 256 + t];
  }
  __syncthreads();
  if (t < 64) {  // (vq, vk, h) dot products, length 32
    int vq = t >> 4, vk = (t >> 2) & 3, h = t & 3;
    float acc = 0.f;
#pragma unroll
    for (int kd = 0; kd < 32; ++kd)
      acc += qs[li][vq][h * 32 + kd] * ks[li][vk][h * 32 + kd];
    aw[li][vq][h][vk] = acc * 0.17677669529663687f;  // 1/sqrt(32)
  }
  __syncthreads();
  if (t < 16) {  // softmax over vk per (vq, h)
    int vq = t >> 2, h = t & 3;
    float mx = aw[li][vq][h][0];
    for (int i = 1; i < 4; ++i) mx = fmaxf(mx, aw[li][vq][h][i]);
    float e[4], s = 0.f;
    for (int i = 0; i < 4; ++i) { e[i] = __expf(aw[li][vq][h][i] - mx); s += e[i]; }
    for (int i = 0; i < 4; ++i) aw[li][vq][h][i] = e[i] / s;
  }
  __syncthreads();
  {
    int h = t >> 5;
#pragma unroll
    for (int vq = 0; vq < 4; ++vq) {
      float acc = 0.f;
#pragma unroll
      for (int vk = 0; vk < 4; ++vk) acc += aw[li][vq][h][vk] * vs[li][vk][t];
      ao_s[li][vq][t] = acc;
    }
  }
  // ---- fused out_proj: out[row][j] = sum_k ao[row][k]*outw[j][k] + outb + bias
  float accp[4];
  float base_b = outb[t] + bias[t];
#pragma unroll
  for (int vq = 0; vq < 4; ++vq) accp[vq] = base_b;
  const float4* outw4 = (const float4*)outw;   // [j][32] float4 (k-groups)
  const float4* ao4 = (const float4*)&ao_s[li][0][0];  // [vq][32] float4
  for (int p = 0; p < 2; ++p) {   // k-halves of 64
    __syncthreads();              // protect owt reuse + ao_s ready (p==0)
    for (int it = 0; it < 8; ++it) {       // stage half p: 2048 float4s
      int idx = tid + it * 256;
      int j = idx >> 4, k4 = idx & 15;
      float4 w = outw4[j * 32 + p * 16 + k4];
      *(float4*)&owt[(j * 16 + ((k4 + j) & 15)) * 4] = w;
    }
    __syncthreads();
#pragma unroll 4
    for (int k4 = 0; k4 < 16; ++k4) {
      float4 w = *(const float4*)&owt[(t * 16 + ((k4 + t) & 15)) * 4];
#pragma unroll
      for (int vq = 0; vq < 4; ++vq) {
        float4 a = ao4[vq * 32 + p * 16 + k4];
        accp[vq] += a.x * w.x + a.y * w.y + a.z * w.z + a.w * w.w;
      }
    }
  }
  // write with (b,v,n) remap: row node*4+vq -> (b*4+vq)*1000+n
#pragma unroll
  for (int vq = 0; vq < 4; ++vq)
    out[((size_t)(b * 4 + vq) * NN + n) * DM + t] = accp[vq];
}

extern "C" void kernel_launch(void* const* d_in, const int* in_sizes, int n_in,
                              void* d_out, int out_size, void* d_ws, size_t ws_size,
                              hipStream_t stream) {
  const float* x    = (const float*)d_in[0];
  const float* W    = (const float*)d_in[1];
  const float* att  = (const float*)d_in[2];
  const float* inw  = (const float*)d_in[3];
  const float* inb  = (const float*)d_in[4];
  const float* outw = (const float*)d_in[5];
  const float* outb = (const float*)d_in[6];
  const float* bias = (const float*)d_in[7];
  const int*   ei   = (const int*)d_in[8];
  float* out = (float*)d_out;

  float* ws = (float*)d_ws;
  float* hbuf  = ws;                       // 2,048,000  (b,v,n)-major h
  float* hgat  = ws + 2100000;             // 2,048,000  node-major
  float* qkv   = ws + 4200000;             // 6,144,000  node-major
  float* ssrc  = ws + 10400000;            // 16,000 } contiguous:
  float* sdst  = ssrc + 16000;             // 16,000 } one 144 KB memset
  int*   cnt   = (int*)(sdst + 16000);     //  4,000 }
  int*   elist = cnt + 4000;               // 192,000 (4000 x CAP)

  // zero ssrc/sdst (rows >=1000 must stay zero) + cnt
  hipMemsetAsync(ssrc, 0, 36000 * sizeof(float), stream);

  k1_kernel<<<250 + EB, 256, 0, stream>>>(x, W, att, hbuf, ssrc, sdst, ei, cnt, elist);
  gather_kernel<<<NTOT / 2, 256, 0, stream>>>(cnt, elist, ssrc, sdst, hbuf, hgat);
  qkv_kernel<<<dim3(125, 6), 256, 0, stream>>>(hgat, inw, inb, qkv);
  attn_out_kernel<<<NTOT / 2, 256, 0, stream>>>(qkv, outw, outb, bias, out);
}

// Round 13
// 153.711 us; speedup vs baseline: 1.0020x; 1.0020x over previous
//
#include <hip/hip_runtime.h>

#define NN 1000
#define HEADS_ 4
#define DM 128
#define EE 64000
#define NTOT 4000
#define ETOT 68000
#define CAP 48     // bucket: deg ~ Poisson(16)+1, P(>=48) ~ 1e-11
#define EB 34      // edge-builder blocks appended to k1

// ---------------------------------------------------------------------------
// Tiled GEMM tile: C[m0..+128][n0..+64] = A @ Wt^T (+b1+b2), K in {64,128}.
// LDS m-major with k-group swizzle g = q ^ ((r>>2)&15) (all accesses <=2-way).
// SCORE: GAT score epilogue (h rows<1000 are the only nonzero h_flat rows).
// REMAP 0: C row = m (A's row order, (b,v,n))
// REMAP 1: C row = (b*4+v)*1000+n   (final output order, from node-major m)
// REMAP 2: C row = (b*1000+n)*4+v   ((b,n,v)-major hbuf, from (b,v,n) m)
// ---------------------------------------------------------------------------
template <int K, int SCORE, int REMAP>
__device__ void gemm_tile(int mi, int ni,
                          const float* __restrict__ A, const float* __restrict__ Wt,
                          const float* __restrict__ b1, const float* __restrict__ b2,
                          float* __restrict__ C, int N,
                          const float* __restrict__ att,
                          float* __restrict__ ssrc, float* __restrict__ sdst) {
  __shared__ float As[128 * 64];
  __shared__ float Bs[64 * 64];
  int tid = threadIdx.x;
  int m0 = mi * 128, n0 = ni * 64;
  int tx = tid & 15, ty = tid >> 4;
  const float4* A4 = (const float4*)A;
  const float4* W4 = (const float4*)Wt;
  float acc[8][4] = {};

  for (int c = 0; c < K / 64; ++c) {
    __syncthreads();
    {
      int q = tid & 15;   // k-group slot within chunk
      int r0 = tid >> 4;  // 16 rows per pass
#pragma unroll
      for (int p = 0; p < 8; ++p) {  // A: 128 rows
        int r = r0 + p * 16;
        float4 v = A4[(size_t)(m0 + r) * (K / 4) + c * 16 + q];
        *(float4*)&As[r * 64 + ((q ^ ((r >> 2) & 15)) << 2)] = v;
      }
#pragma unroll
      for (int p = 0; p < 4; ++p) {  // B: 64 rows
        int r = r0 + p * 16;
        float4 v = W4[(size_t)(n0 + r) * (K / 4) + c * 16 + q];
        *(float4*)&Bs[r * 64 + ((q ^ ((r >> 2) & 15)) << 2)] = v;
      }
    }
    __syncthreads();
#pragma unroll 4
    for (int q = 0; q < 16; ++q) {
      float4 a[8], b[4];
#pragma unroll
      for (int i = 0; i < 8; ++i) {
        int r = ty * 8 + i;
        a[i] = *(const float4*)&As[r * 64 + ((q ^ ((r >> 2) & 15)) << 2)];
      }
#pragma unroll
      for (int j = 0; j < 4; ++j) {
        int rn = tx * 4 + j;
        b[j] = *(const float4*)&Bs[rn * 64 + ((q ^ ((rn >> 2) & 15)) << 2)];
      }
#pragma unroll
      for (int i = 0; i < 8; ++i)
#pragma unroll
        for (int j = 0; j < 4; ++j)
          acc[i][j] += a[i].x * b[j].x + a[i].y * b[j].y
                     + a[i].z * b[j].z + a[i].w * b[j].w;
    }
  }

  float bd[4] = {0.f, 0.f, 0.f, 0.f};
  int nc = n0 + tx * 4;
  if (b1) { bd[0] = b1[nc]; bd[1] = b1[nc+1]; bd[2] = b1[nc+2]; bd[3] = b1[nc+3]; }
  if (b2) { bd[0] += b2[nc]; bd[1] += b2[nc+1]; bd[2] += b2[nc+2]; bd[3] += b2[nc+3]; }
#pragma unroll
  for (int i = 0; i < 8; ++i) {
    int m = m0 + ty * 8 + i;
    int om = m;
    if (REMAP == 1) {         // m = node*4+v (node-major) -> (b*4+v)*1000+n
      int node = m >> 2, v = m & 3;
      int b = node / NN, n = node - b * NN;
      om = (b * 4 + v) * NN + n;
    } else if (REMAP == 2) {  // m = (b*4+v)*1000+n -> (b*1000+n)*4+v
      int b = m / 4000, rem = m - b * 4000;
      int v = rem / NN, n = rem - v * NN;
      om = (b * NN + n) * 4 + v;
    }
    float4 o = make_float4(acc[i][0] + bd[0], acc[i][1] + bd[1],
                           acc[i][2] + bd[2], acc[i][3] + bd[3]);
    *(float4*)&C[(size_t)om * N + nc] = o;
  }

  if (SCORE && m0 < NN) {  // uniform per block (m<1000 => b=0,v=0, node id = m)
    int hsel = tx >> 3;
    int h = ni * 2 + hsel;
    int kb = (tx & 7) * 4;
    float a0[4], a1[4];
#pragma unroll
    for (int j = 0; j < 4; ++j) {
      a0[j] = att[h * 64 + kb + j];
      a1[j] = att[h * 64 + 32 + kb + j];
    }
#pragma unroll
    for (int i = 0; i < 8; ++i) {
      int m = m0 + ty * 8 + i;
      float p0 = 0.f, p1 = 0.f;
#pragma unroll
      for (int j = 0; j < 4; ++j) {
        float g = acc[i][j];
        float lr = g > 0.f ? g : 0.2f * g;
        p0 += a0[j] * lr;
        p1 += a1[j] * lr;
      }
      p0 += __shfl_xor(p0, 1, 16); p1 += __shfl_xor(p1, 1, 16);
      p0 += __shfl_xor(p0, 2, 16); p1 += __shfl_xor(p1, 2, 16);
      p0 += __shfl_xor(p0, 4, 16); p1 += __shfl_xor(p1, 4, 16);
      if ((tx & 7) == 0 && m < NN) {
        ssrc[m * HEADS_ + h] = p0;
        sdst[m * HEADS_ + h] = p1;
      }
    }
  }
}

// -------- K1: blocks 0..249 = h-GEMM (125x2 tiles, (b,n,v)-major out) + score
//              blocks 250..249+EB = bucket build
__global__ __launch_bounds__(256) void k1_kernel(const float* __restrict__ x,
                                                 const float* __restrict__ W,
                                                 const float* __restrict__ att,
                                                 float* __restrict__ hbuf,
                                                 float* __restrict__ ssrc,
                                                 float* __restrict__ sdst,
                                                 const int* __restrict__ ei,
                                                 int* __restrict__ cnt,
                                                 int* __restrict__ elist) {
  int bid = blockIdx.x;
  if (bid < 250) {
    gemm_tile<64, 1, 2>(bid >> 1, bid & 1, x, W, nullptr, nullptr, hbuf, 128,
                        att, ssrc, sdst);
  } else {
    for (int e = (bid - 250) * 256 + threadIdx.x; e < ETOT; e += EB * 256) {
      int s, d;
      if (e < EE) { s = ei[e]; d = ei[EE + e]; }
      else { s = d = e - EE; }  // self loops
      int pos = atomicAdd(&cnt[d], 1);
      if (pos < CAP) elist[d * CAP + pos] = s;
    }
  }
}

// -------- K2: gather with in-block softmax (local denom), 2 dst/block.
// hbuf is (b,n,v)-major: 4 views of a src node are 2KB contiguous -> a pair's
// 128 threads read 2 contiguous 1KB bursts per edge (was 4 x 512KB-strided).
__global__ __launch_bounds__(256) void gather_kernel(const int* __restrict__ cnt,
                                                     const int* __restrict__ elist,
                                                     const float* __restrict__ ssrc,
                                                     const float* __restrict__ sdst,
                                                     const float* __restrict__ hbuf,
                                                     float* __restrict__ hgat) {
  __shared__ int   srcs[2][CAP];
  __shared__ float exs[2][CAP][HEADS_];
  int li = threadIdx.x >> 7;
  int t = threadIdx.x & 127;
  int d = blockIdx.x * 2 + li;  // global dst node id
  int b = d / NN;
  int v = t >> 5, q = t & 31, h = q >> 3;
  int m = cnt[d]; if (m > CAP) m = CAP;
  for (int base = 0; base < m; base += 32) {  // 4 threads per edge
    int i = base + (t >> 2);
    if (i < m) {
      int s = elist[d * CAP + i];
      if ((t & 3) == 0) srcs[li][i] = s;
      float sc = ssrc[s * HEADS_ + (t & 3)] + sdst[d * HEADS_ + (t & 3)];
      exs[li][i][t & 3] = __expf(sc);  // shift-invariant, scores O(1)
    }
  }
  __syncthreads();
  // denom over ALL edges; numerator over same-block srcs (h_full block-diag)
  float den = 1e-16f;
  float4 acc = make_float4(0.f, 0.f, 0.f, 0.f);
  // row (b*NN+sl)*4+v, col q*4 : base addr + sl*512 floats
  const float* hbase = hbuf + ((size_t)b * NN * 4 + v) * DM + q * 4;
  for (int i = 0; i < m; ++i) {
    float ex = exs[li][i][h];
    den += ex;
    unsigned sl = (unsigned)(srcs[li][i] - b * NN);
    if (sl < NN) {
      float4 hv = *(const float4*)(hbase + (size_t)sl * (4 * DM));
      acc.x += ex * hv.x; acc.y += ex * hv.y;
      acc.z += ex * hv.z; acc.w += ex * hv.w;
    }
  }
  float r = 1.f / den;
  acc.x *= r; acc.y *= r; acc.z *= r; acc.w *= r;
  *(float4*)&hgat[((size_t)(d * 4 + v)) * DM + q * 4] = acc;  // node-major
}

// -------- K3: qkv GEMM wrapper (node-major, M=16000, K=128, N=384)
__global__ __launch_bounds__(256) void qkv_kernel(const float* __restrict__ hgat,
                                                  const float* __restrict__ inw,
                                                  const float* __restrict__ inb,
                                                  float* __restrict__ qkv) {
  gemm_tile<128, 0, 0>(blockIdx.x, blockIdx.y, hgat, inw, inb, nullptr, qkv,
                       384, nullptr, nullptr, nullptr);
}

// -------- K4: attention over V, 2 nodes/block, node-major qkv/ao
__global__ __launch_bounds__(256) void attn_kernel(const float* __restrict__ qkv,
                                                   float* __restrict__ ao) {
  int li = threadIdx.x >> 7;
  int t = threadIdx.x & 127;
  int node = blockIdx.x * 2 + li;  // 0..3999
  __shared__ float qs[2][4][DM], ks[2][4][DM], vs[2][4][DM];
  __shared__ float aw[2][4][HEADS_][4];
#pragma unroll
  for (int v = 0; v < 4; ++v) {
    size_t base = (size_t)(node * 4 + v) * 384;  // contiguous rows
    qs[li][v][t] = qkv[base + t];
    ks[li][v][t] = qkv[base + 128 + t];
    vs[li][v][t] = qkv[base + 256 + t];
  }
  __syncthreads();
  if (t < 64) {  // (vq, vk, h) dot products, length 32
    int vq = t >> 4, vk = (t >> 2) & 3, h = t & 3;
    float acc = 0.f;
#pragma unroll
    for (int kd = 0; kd < 32; ++kd)
      acc += qs[li][vq][h * 32 + kd] * ks[li][vk][h * 32 + kd];
    aw[li][vq][h][vk] = acc * 0.17677669529663687f;  // 1/sqrt(32)
  }
  __syncthreads();
  if (t < 16) {  // softmax over vk per (vq, h)
    int vq = t >> 2, h = t & 3;
    float mx = aw[li][vq][h][0];
    for (int i = 1; i < 4; ++i) mx = fmaxf(mx, aw[li][vq][h][i]);
    float e[4], s = 0.f;
    for (int i = 0; i < 4; ++i) { e[i] = __expf(aw[li][vq][h][i] - mx); s += e[i]; }
    for (int i = 0; i < 4; ++i) aw[li][vq][h][i] = e[i] / s;
  }
  __syncthreads();
  int h = t >> 5;
#pragma unroll
  for (int vq = 0; vq < 4; ++vq) {
    float acc = 0.f;
#pragma unroll
    for (int vk = 0; vk < 4; ++vk) acc += aw[li][vq][h][vk] * vs[li][vk][t];
    ao[(size_t)(node * 4 + vq) * DM + t] = acc;
  }
}

// -------- K5: out_proj GEMM, remap rows to (b,v,n) output order
__global__ __launch_bounds__(256) void outproj_kernel(const float* __restrict__ ao,
                                                      const float* __restrict__ outw,
                                                      const float* __restrict__ outb,
                                                      const float* __restrict__ bias,
                                                      float* __restrict__ out) {
  gemm_tile<128, 0, 1>(blockIdx.x, blockIdx.y, ao, outw, outb, bias, out, 128,
                       nullptr, nullptr, nullptr);
}

extern "C" void kernel_launch(void* const* d_in, const int* in_sizes, int n_in,
                              void* d_out, int out_size, void* d_ws, size_t ws_size,
                              hipStream_t stream) {
  const float* x    = (const float*)d_in[0];
  const float* W    = (const float*)d_in[1];
  const float* att  = (const float*)d_in[2];
  const float* inw  = (const float*)d_in[3];
  const float* inb  = (const float*)d_in[4];
  const float* outw = (const float*)d_in[5];
  const float* outb = (const float*)d_in[6];
  const float* bias = (const float*)d_in[7];
  const int*   ei   = (const int*)d_in[8];
  float* out = (float*)d_out;

  float* ws = (float*)d_ws;
  float* hbuf  = ws;                       // 2,048,000  (b,n,v)-major h
  float* hgat  = ws + 2100000;             // 2,048,000  node-major
  float* qkv   = ws + 4200000;             // 6,144,000  node-major
  float* ao    = ws + 10400000;            // 2,048,000  node-major
  float* ssrc  = ws + 12500000;            // 16,000 } contiguous:
  float* sdst  = ssrc + 16000;             // 16,000 } one 144 KB memset
  int*   cnt   = (int*)(sdst + 16000);     //  4,000 }
  int*   elist = cnt + 4000;               // 192,000 (4000 x CAP)

  // zero ssrc/sdst (rows >=1000 must stay zero) + cnt
  hipMemsetAsync(ssrc, 0, 36000 * sizeof(float), stream);

  k1_kernel<<<250 + EB, 256, 0, stream>>>(x, W, att, hbuf, ssrc, sdst, ei, cnt, elist);
  gather_kernel<<<NTOT / 2, 256, 0, stream>>>(cnt, elist, ssrc, sdst, hbuf, hgat);
  qkv_kernel<<<dim3(125, 6), 256, 0, stream>>>(hgat, inw, inb, qkv);
  attn_kernel<<<NTOT / 2, 256, 0, stream>>>(qkv, ao);
  outproj_kernel<<<dim3(125, 2), 256, 0, stream>>>(ao, outw, outb, bias, out);
}

// Round 14
// 151.711 us; speedup vs baseline: 1.0153x; 1.0132x over previous
//
#include <hip/hip_runtime.h>

#define NN 1000
#define HEADS_ 4
#define DM 128
#define EE 64000
#define NTOT 4000
#define ETOT 68000
#define CAP 48     // bucket holds ALL edges per dst: deg ~ Poisson(16)+1, P(>=48) ~ 1e-11
#define EB 34      // edge-builder blocks appended to the h-GEMM dispatch

// ---------------------------------------------------------------------------
// Tiled GEMM tile: C[m0..+128][n0..+64] = A @ Wt^T (+b1+b2), K in {64,128}.
// LDS m-major with k-group swizzle g = q ^ ((r>>2)&15):
//  - staging: 16 threads (q=0..15) per row -> writes cover all 16 groups, free
//  - a-frag reads (rows ty*8+i): 4 addresses/wave, 4 distinct bank-groups, free
//  - b-frag reads (rows tx*4+j): 16 addresses/wave, 16 distinct groups, 2-way
//    (free per m136).
// SCORE: fused GAT score epilogue (h-GEMM; only rows<1000 are nonzero h_flat).
// REMAP: write row m=node*4+v to (b*4+v)*1000+n order (final output layout).
// ---------------------------------------------------------------------------
template <int K, int SCORE, int REMAP>
__device__ void gemm_tile(int mi, int ni,
                          const float* __restrict__ A, const float* __restrict__ Wt,
                          const float* __restrict__ b1, const float* __restrict__ b2,
                          float* __restrict__ C, int N,
                          const float* __restrict__ att,
                          float* __restrict__ ssrc, float* __restrict__ sdst) {
  __shared__ float As[128 * 64];
  __shared__ float Bs[64 * 64];
  int tid = threadIdx.x;
  int m0 = mi * 128, n0 = ni * 64;
  int tx = tid & 15, ty = tid >> 4;
  const float4* A4 = (const float4*)A;
  const float4* W4 = (const float4*)Wt;
  float acc[8][4] = {};

  for (int c = 0; c < K / 64; ++c) {
    __syncthreads();
    {
      int q = tid & 15;   // k-group slot within chunk
      int r0 = tid >> 4;  // 16 rows per pass
#pragma unroll
      for (int p = 0; p < 8; ++p) {  // A: 128 rows
        int r = r0 + p * 16;
        float4 v = A4[(size_t)(m0 + r) * (K / 4) + c * 16 + q];
        *(float4*)&As[r * 64 + ((q ^ ((r >> 2) & 15)) << 2)] = v;
      }
#pragma unroll
      for (int p = 0; p < 4; ++p) {  // B: 64 rows
        int r = r0 + p * 16;
        float4 v = W4[(size_t)(n0 + r) * (K / 4) + c * 16 + q];
        *(float4*)&Bs[r * 64 + ((q ^ ((r >> 2) & 15)) << 2)] = v;
      }
    }
    __syncthreads();
#pragma unroll 4
    for (int q = 0; q < 16; ++q) {
      float4 a[8], b[4];
#pragma unroll
      for (int i = 0; i < 8; ++i) {
        int r = ty * 8 + i;
        a[i] = *(const float4*)&As[r * 64 + ((q ^ ((r >> 2) & 15)) << 2)];
      }
#pragma unroll
      for (int j = 0; j < 4; ++j) {
        int rn = tx * 4 + j;
        b[j] = *(const float4*)&Bs[rn * 64 + ((q ^ ((rn >> 2) & 15)) << 2)];
      }
#pragma unroll
      for (int i = 0; i < 8; ++i)
#pragma unroll
        for (int j = 0; j < 4; ++j)
          acc[i][j] += a[i].x * b[j].x + a[i].y * b[j].y
                     + a[i].z * b[j].z + a[i].w * b[j].w;
    }
  }

  float bd[4] = {0.f, 0.f, 0.f, 0.f};
  int nc = n0 + tx * 4;
  if (b1) { bd[0] = b1[nc]; bd[1] = b1[nc+1]; bd[2] = b1[nc+2]; bd[3] = b1[nc+3]; }
  if (b2) { bd[0] += b2[nc]; bd[1] += b2[nc+1]; bd[2] += b2[nc+2]; bd[3] += b2[nc+3]; }
#pragma unroll
  for (int i = 0; i < 8; ++i) {
    int m = m0 + ty * 8 + i;
    int om = m;
    if (REMAP) {
      int node = m >> 2, v = m & 3;
      int b = node / NN, n = node - b * NN;
      om = (b * 4 + v) * NN + n;
    }
    float4 o = make_float4(acc[i][0] + bd[0], acc[i][1] + bd[1],
                           acc[i][2] + bd[2], acc[i][3] + bd[3]);
    *(float4*)&C[(size_t)om * N + nc] = o;
  }

  if (SCORE && m0 < NN) {  // uniform per block
    int hsel = tx >> 3;
    int h = ni * 2 + hsel;
    int kb = (tx & 7) * 4;
    float a0[4], a1[4];
#pragma unroll
    for (int j = 0; j < 4; ++j) {
      a0[j] = att[h * 64 + kb + j];
      a1[j] = att[h * 64 + 32 + kb + j];
    }
#pragma unroll
    for (int i = 0; i < 8; ++i) {
      int m = m0 + ty * 8 + i;
      float p0 = 0.f, p1 = 0.f;
#pragma unroll
      for (int j = 0; j < 4; ++j) {
        float g = acc[i][j];
        float lr = g > 0.f ? g : 0.2f * g;
        p0 += a0[j] * lr;
        p1 += a1[j] * lr;
      }
      p0 += __shfl_xor(p0, 1, 16); p1 += __shfl_xor(p1, 1, 16);
      p0 += __shfl_xor(p0, 2, 16); p1 += __shfl_xor(p1, 2, 16);
      p0 += __shfl_xor(p0, 4, 16); p1 += __shfl_xor(p1, 4, 16);
      if ((tx & 7) == 0 && m < NN) {
        ssrc[m * HEADS_ + h] = p0;
        sdst[m * HEADS_ + h] = p1;
      }
    }
  }
}

// -------- K1: blocks 0..249 = h-GEMM (125 m-tiles x 2 n-tiles) + score
//              blocks 250..249+EB = bucket build
__global__ __launch_bounds__(256) void k1_kernel(const float* __restrict__ x,
                                                 const float* __restrict__ W,
                                                 const float* __restrict__ att,
                                                 float* __restrict__ hbuf,
                                                 float* __restrict__ ssrc,
                                                 float* __restrict__ sdst,
                                                 const int* __restrict__ ei,
                                                 int* __restrict__ cnt,
                                                 int* __restrict__ elist) {
  int bid = blockIdx.x;
  if (bid < 250) {
    gemm_tile<64, 1, 0>(bid >> 1, bid & 1, x, W, nullptr, nullptr, hbuf, 128,
                        att, ssrc, sdst);
  } else {
    for (int e = (bid - 250) * 256 + threadIdx.x; e < ETOT; e += EB * 256) {
      int s, d;
      if (e < EE) { s = ei[e]; d = ei[EE + e]; }
      else { s = d = e - EE; }  // self loops
      int pos = atomicAdd(&cnt[d], 1);
      if (pos < CAP) elist[d * CAP + pos] = s;
    }
  }
}

// -------- K2: gather with in-block softmax (local denom), 2 dst/block
__global__ __launch_bounds__(256) void gather_kernel(const int* __restrict__ cnt,
                                                     const int* __restrict__ elist,
                                                     const float* __restrict__ ssrc,
                                                     const float* __restrict__ sdst,
                                                     const float* __restrict__ hbuf,
                                                     float* __restrict__ hgat) {
  __shared__ int   srcs[2][CAP];
  __shared__ float exs[2][CAP][HEADS_];
  int li = threadIdx.x >> 7;
  int t = threadIdx.x & 127;
  int d = blockIdx.x * 2 + li;  // global dst node id
  int b = d / NN;
  int v = t >> 5, q = t & 31, h = q >> 3;
  int m = cnt[d]; if (m > CAP) m = CAP;
  // stage src ids + exp(score per head): 4 threads per edge
  for (int base = 0; base < m; base += 32) {
    int i = base + (t >> 2);
    if (i < m) {
      int s = elist[d * CAP + i];
      if ((t & 3) == 0) srcs[li][i] = s;
      float sc = ssrc[s * HEADS_ + (t & 3)] + sdst[d * HEADS_ + (t & 3)];
      exs[li][i][t & 3] = __expf(sc);  // shift-invariant, scores O(1)
    }
  }
  __syncthreads();
  // denom over ALL edges; numerator over same-block srcs (h_full block-diag)
  float den = 1e-16f;
  float4 acc = make_float4(0.f, 0.f, 0.f, 0.f);
  const float* hbase = hbuf + ((size_t)(b * 4 + v) * NN) * DM + q * 4;
  for (int i = 0; i < m; ++i) {
    float ex = exs[li][i][h];
    den += ex;
    unsigned sl = (unsigned)(srcs[li][i] - b * NN);
    if (sl < NN) {
      float4 hv = *(const float4*)(hbase + (size_t)sl * DM);
      acc.x += ex * hv.x; acc.y += ex * hv.y;
      acc.z += ex * hv.z; acc.w += ex * hv.w;
    }
  }
  float r = 1.f / den;
  acc.x *= r; acc.y *= r; acc.z *= r; acc.w *= r;
  *(float4*)&hgat[((size_t)(d * 4 + v)) * DM + q * 4] = acc;  // node-major
}

// -------- K3: qkv GEMM wrapper (node-major, M=16000, K=128, N=384)
__global__ __launch_bounds__(256) void qkv_kernel(const float* __restrict__ hgat,
                                                  const float* __restrict__ inw,
                                                  const float* __restrict__ inb,
                                                  float* __restrict__ qkv) {
  gemm_tile<128, 0, 0>(blockIdx.x, blockIdx.y, hgat, inw, inb, nullptr, qkv,
                       384, nullptr, nullptr, nullptr);
}

// -------- K4: attention over V, 2 nodes/block, node-major qkv/ao
__global__ __launch_bounds__(256) void attn_kernel(const float* __restrict__ qkv,
                                                   float* __restrict__ ao) {
  int li = threadIdx.x >> 7;
  int t = threadIdx.x & 127;
  int node = blockIdx.x * 2 + li;  // 0..3999
  __shared__ float qs[2][4][DM], ks[2][4][DM], vs[2][4][DM];
  __shared__ float aw[2][4][HEADS_][4];
#pragma unroll
  for (int v = 0; v < 4; ++v) {
    size_t base = (size_t)(node * 4 + v) * 384;  // contiguous rows
    qs[li][v][t] = qkv[base + t];
    ks[li][v][t] = qkv[base + 128 + t];
    vs[li][v][t] = qkv[base + 256 + t];
  }
  __syncthreads();
  if (t < 64) {  // (vq, vk, h) dot products, length 32
    int vq = t >> 4, vk = (t >> 2) & 3, h = t & 3;
    float acc = 0.f;
#pragma unroll
    for (int kd = 0; kd < 32; ++kd)
      acc += qs[li][vq][h * 32 + kd] * ks[li][vk][h * 32 + kd];
    aw[li][vq][h][vk] = acc * 0.17677669529663687f;  // 1/sqrt(32)
  }
  __syncthreads();
  if (t < 16) {  // softmax over vk per (vq, h)
    int vq = t >> 2, h = t & 3;
    float mx = aw[li][vq][h][0];
    for (int i = 1; i < 4; ++i) mx = fmaxf(mx, aw[li][vq][h][i]);
    float e[4], s = 0.f;
    for (int i = 0; i < 4; ++i) { e[i] = __expf(aw[li][vq][h][i] - mx); s += e[i]; }
    for (int i = 0; i < 4; ++i) aw[li][vq][h][i] = e[i] / s;
  }
  __syncthreads();
  int h = t >> 5;
#pragma unroll
  for (int vq = 0; vq < 4; ++vq) {
    float acc = 0.f;
#pragma unroll
    for (int vk = 0; vk < 4; ++vk) acc += aw[li][vq][h][vk] * vs[li][vk][t];
    ao[(size_t)(node * 4 + vq) * DM + t] = acc;
  }
}

// -------- K5: out_proj GEMM wrapper, remap rows to (b,v,n) output order
__global__ __launch_bounds__(256) void outproj_kernel(const float* __restrict__ ao,
                                                      const float* __restrict__ outw,
                                                      const float* __restrict__ outb,
                                                      const float* __restrict__ bias,
                                                      float* __restrict__ out) {
  gemm_tile<128, 0, 1>(blockIdx.x, blockIdx.y, ao, outw, outb, bias, out, 128,
                       nullptr, nullptr, nullptr);
}

extern "C" void kernel_launch(void* const* d_in, const int* in_sizes, int n_in,
                              void* d_out, int out_size, void* d_ws, size_t ws_size,
                              hipStream_t stream) {
  const float* x    = (const float*)d_in[0];
  const float* W    = (const float*)d_in[1];
  const float* att  = (const float*)d_in[2];
  const float* inw  = (const float*)d_in[3];
  const float* inb  = (const float*)d_in[4];
  const float* outw = (const float*)d_in[5];
  const float* outb = (const float*)d_in[6];
  const float* bias = (const float*)d_in[7];
  const int*   ei   = (const int*)d_in[8];
  float* out = (float*)d_out;

  float* ws = (float*)d_ws;
  float* hbuf  = ws;                       // 2,048,000  (b,v,n)-major h
  float* hgat  = ws + 2100000;             // 2,048,000  node-major
  float* qkv   = ws + 4200000;             // 6,144,000  node-major
  float* ao    = ws + 10400000;            // 2,048,000  node-major
  float* ssrc  = ws + 12500000;            // 16,000 } contiguous:
  float* sdst  = ssrc + 16000;             // 16,000 } one 144 KB memset
  int*   cnt   = (int*)(sdst + 16000);     //  4,000 }
  int*   elist = cnt + 4000;               // 192,000 (4000 x CAP)

  // zero ssrc/sdst (rows >=1000 must stay zero) + cnt
  hipMemsetAsync(ssrc, 0, 36000 * sizeof(float), stream);

  k1_kernel<<<250 + EB, 256, 0, stream>>>(x, W, att, hbuf, ssrc, sdst, ei, cnt, elist);
  gather_kernel<<<NTOT / 2, 256, 0, stream>>>(cnt, elist, ssrc, sdst, hbuf, hgat);
  qkv_kernel<<<dim3(125, 6), 256, 0, stream>>>(hgat, inw, inb, qkv);
  attn_kernel<<<NTOT / 2, 256, 0, stream>>>(qkv, ao);
  outproj_kernel<<<dim3(125, 2), 256, 0, stream>>>(ao, outw, outb, bias, out);
}